// Round 11
// baseline (236.302 us; speedup 1.0000x reference)
//
#include <hip/hip_runtime.h>
#include <hip/hip_fp16.h>
#include <math.h>

#define N_NODES 100000
#define N_EDGES 1600000
#define FIN 256
#define NB 196           // ceil(100000/512): 512-node dst buckets
#define CAP 10240        // bucket capacity: mean 8163, sigma ~90 -> +22 sigma
#define NFILL 391        // ceil(E/4096) fill blocks
#define NGEMM 782        // ceil(N/128) gemm1 blocks

typedef _Float16 h8 __attribute__((ext_vector_type(8)));
typedef float f4 __attribute__((ext_vector_type(4)));

// ---------------- degree + dinv (needed by gemm1 before sort_bins runs) ----------------
__global__ __launch_bounds__(256) void k_count_deg(const int* __restrict__ dst, int* __restrict__ degi) {
    int e = blockIdx.x * 256 + threadIdx.x;
    if (e < N_EDGES) atomicAdd(&degi[dst[e]], 1);
}
__global__ __launch_bounds__(256) void k_dinv(const int* __restrict__ degi, float* __restrict__ dinv) {
    int i = blockIdx.x * 256 + threadIdx.x;
    if (i < N_NODES) dinv[i] = rsqrtf((float)degi[i] + 1.0f);
}

// ---------------- W1 -> f16 MFMA B-fragment layout ----------------
__global__ __launch_bounds__(256) void k_prepW1(const float* __restrict__ W1, _Float16* __restrict__ Bfrag) {
    int i = blockIdx.x * 256 + threadIdx.x;   // 0..16383
    int j = i & 7, lane = (i >> 3) & 63, nt = (i >> 9) & 3, ks = i >> 11;
    int k = ks * 32 + ((lane >> 4) << 3) + j;
    int c = nt * 16 + (lane & 15);
    Bfrag[i] = (_Float16)W1[k * 64 + c];
}

// ---------------- merged front: fill_bins blocks (0..NFILL-1) || gemm1 blocks (NFILL..) ----------------
__global__ __launch_bounds__(256) void k_front(const int* __restrict__ src, const int* __restrict__ dst,
                                               int* __restrict__ bcur, int* __restrict__ bpack,
                                               const float* __restrict__ x,
                                               const _Float16* __restrict__ Bfrag,
                                               const float* __restrict__ dinv,
                                               __half* __restrict__ hh) {
    const int tid = threadIdx.x;
    if (blockIdx.x < NFILL) {
        __shared__ int hist[NB], curs[NB], bstart[NB];
        for (int i = tid; i < NB; i += 256) { hist[i] = 0; curs[i] = 0; }
        __syncthreads();
        const int base = blockIdx.x * 4096;
        int eb[16], ee[16];
        #pragma unroll
        for (int k = 0; k < 16; ++k) {
            int e = base + k * 256 + tid;
            eb[k] = -1;
            if (e < N_EDGES) {
                int s = src[e], d = dst[e];
                int b = d >> 9;
                eb[k] = b;
                ee[k] = ((d & 511) << 17) | s;
                atomicAdd(&hist[b], 1);
            }
        }
        __syncthreads();
        for (int i = tid; i < NB; i += 256)
            if (hist[i] > 0) bstart[i] = i * CAP + atomicAdd(&bcur[i], hist[i]);
        __syncthreads();
        #pragma unroll
        for (int k = 0; k < 16; ++k) {
            if (eb[k] >= 0) {
                int r = atomicAdd(&curs[eb[k]], 1);
                bpack[bstart[eb[k]] + r] = ee[k];
            }
        }
    } else {
        const int bid = blockIdx.x - NFILL;
        const int wave = tid >> 6, lane = tid & 63;
        const int lrow = lane & 15;
        const int lk = lane >> 4;
        const int row0 = bid * 128 + wave * 16 + lrow;
        const int row1 = row0 + 64;
        const int rc0 = (row0 < N_NODES) ? row0 : (N_NODES - 1);
        const int rc1 = (row1 < N_NODES) ? row1 : (N_NODES - 1);
        const float di0 = dinv[rc0];
        const float di1 = dinv[rc1];
        const float* xp0 = x + (size_t)rc0 * 256 + lk * 8;
        const float* xp1 = x + (size_t)rc1 * 256 + lk * 8;
        const h8* bp = (const h8*)Bfrag + lane;

        f4 accA0 = {0.f,0.f,0.f,0.f}, accA1 = {0.f,0.f,0.f,0.f};
        f4 accA2 = {0.f,0.f,0.f,0.f}, accA3 = {0.f,0.f,0.f,0.f};
        f4 accB0 = {0.f,0.f,0.f,0.f}, accB1 = {0.f,0.f,0.f,0.f};
        f4 accB2 = {0.f,0.f,0.f,0.f}, accB3 = {0.f,0.f,0.f,0.f};

        #pragma unroll 2
        for (int ks = 0; ks < 8; ++ks) {
            float4 a01 = *(const float4*)(xp0 + ks * 32);
            float4 a23 = *(const float4*)(xp0 + ks * 32 + 4);
            float4 c01 = *(const float4*)(xp1 + ks * 32);
            float4 c23 = *(const float4*)(xp1 + ks * 32 + 4);
            h8 afA, afB;
            afA[0] = (_Float16)(a01.x * di0); afA[1] = (_Float16)(a01.y * di0);
            afA[2] = (_Float16)(a01.z * di0); afA[3] = (_Float16)(a01.w * di0);
            afA[4] = (_Float16)(a23.x * di0); afA[5] = (_Float16)(a23.y * di0);
            afA[6] = (_Float16)(a23.z * di0); afA[7] = (_Float16)(a23.w * di0);
            afB[0] = (_Float16)(c01.x * di1); afB[1] = (_Float16)(c01.y * di1);
            afB[2] = (_Float16)(c01.z * di1); afB[3] = (_Float16)(c01.w * di1);
            afB[4] = (_Float16)(c23.x * di1); afB[5] = (_Float16)(c23.y * di1);
            afB[6] = (_Float16)(c23.z * di1); afB[7] = (_Float16)(c23.w * di1);
            h8 b0 = bp[(ks * 4 + 0) * 64];
            h8 b1 = bp[(ks * 4 + 1) * 64];
            h8 b2 = bp[(ks * 4 + 2) * 64];
            h8 b3 = bp[(ks * 4 + 3) * 64];
            accA0 = __builtin_amdgcn_mfma_f32_16x16x32_f16(afA, b0, accA0, 0, 0, 0);
            accB0 = __builtin_amdgcn_mfma_f32_16x16x32_f16(afB, b0, accB0, 0, 0, 0);
            accA1 = __builtin_amdgcn_mfma_f32_16x16x32_f16(afA, b1, accA1, 0, 0, 0);
            accB1 = __builtin_amdgcn_mfma_f32_16x16x32_f16(afB, b1, accB1, 0, 0, 0);
            accA2 = __builtin_amdgcn_mfma_f32_16x16x32_f16(afA, b2, accA2, 0, 0, 0);
            accB2 = __builtin_amdgcn_mfma_f32_16x16x32_f16(afB, b2, accB2, 0, 0, 0);
            accA3 = __builtin_amdgcn_mfma_f32_16x16x32_f16(afA, b3, accA3, 0, 0, 0);
            accB3 = __builtin_amdgcn_mfma_f32_16x16x32_f16(afB, b3, accB3, 0, 0, 0);
        }

        const int orowA = bid * 128 + wave * 16 + lk * 4;
        const int orowB = orowA + 64;
        const bool evlane = ((lane & 1) == 0);
#define STORE_TILE(ACC, NT, OR) { \
        _Pragma("unroll") \
        for (int r = 0; r < 4; ++r) { \
            float v = ACC[r]; \
            float o = __shfl_xor(v, 1); \
            int orow = (OR) + r; \
            if (evlane && orow < N_NODES) \
                *(__half2*)&hh[(size_t)orow * 64 + (NT) * 16 + lrow] = __floats2half2_rn(v, o); \
        } }
        STORE_TILE(accA0, 0, orowA)
        STORE_TILE(accA1, 1, orowA)
        STORE_TILE(accA2, 2, orowA)
        STORE_TILE(accA3, 3, orowA)
        STORE_TILE(accB0, 0, orowB)
        STORE_TILE(accB1, 1, orowB)
        STORE_TILE(accB2, 2, orowB)
        STORE_TILE(accB3, 3, orowB)
#undef STORE_TILE
    }
}

// ---------------- pass B: per bucket -> node histogram, scan, starts/ends, sorted src ----------------
__global__ __launch_bounds__(512) void k_sort_bins(const int* __restrict__ bcur,
                                                   const int* __restrict__ bpack,
                                                   int* __restrict__ pack,
                                                   int* __restrict__ starts,
                                                   int* __restrict__ ends) {
    __shared__ int hist[512], sd[512], cur[512];
    const int tid = threadIdx.x;
    const int b = blockIdx.x;
    const int node0 = b << 9;
    hist[tid] = 0;
    __syncthreads();
    const int s0 = b * CAP, s1 = s0 + bcur[b];
    for (int i = s0 + tid; i < s1; i += 512) atomicAdd(&hist[bpack[i] >> 17], 1);
    __syncthreads();
    const int deg = hist[tid];
    sd[tid] = deg;
    __syncthreads();
    for (int off = 1; off < 512; off <<= 1) {
        int tv = (tid >= off) ? sd[tid - off] : 0;
        __syncthreads();
        sd[tid] += tv;
        __syncthreads();
    }
    const int excl = sd[tid] - deg;
    const int n = node0 + tid;
    cur[tid] = s0 + excl;
    if (n < N_NODES) {
        starts[n] = s0 + excl;
        ends[n]   = s0 + excl + deg;
    }
    __syncthreads();
    for (int i = s0 + tid; i < s1; i += 512) {
        int v = bpack[i];
        int pos = atomicAdd(&cur[v >> 17], 1);
        pack[pos] = v & 0x1FFFF;
    }
}

// ---------------- fused agg1 + self-loop + b1 + relu + GEMM2, h2' = dinv*h2 out ----------------
__global__ __launch_bounds__(256) void k_agg1_gemm2(const int* __restrict__ starts,
                                                    const int* __restrict__ ends,
                                                    const int* __restrict__ pack,
                                                    const float* __restrict__ dinv,
                                                    const __half* __restrict__ hh,
                                                    const float* __restrict__ b1,
                                                    const float* __restrict__ W2,
                                                    __half* __restrict__ h2h) {
    __shared__ float W2s[64][17];
    __shared__ float h1s[4][64];
    const int tid = threadIdx.x;
    for (int i = tid; i < 64 * 16; i += 256) W2s[i >> 4][i & 15] = W2[i];
    __syncthreads();

    const int wave = tid >> 6;
    const int lane = tid & 63;
    const int node = blockIdx.x * 4 + wave;
    const int e4 = lane >> 4;        // edge slot 0..3
    const int l4 = lane & 15;        // channels 4*l4 .. 4*l4+3

    const int s0 = starts[node], s1 = ends[node];
    float4 A = {0.f, 0.f, 0.f, 0.f}, B = {0.f, 0.f, 0.f, 0.f};
    int i = s0;
    for (; i + 7 < s1; i += 8) {
        int p0 = pack[i + e4], p1 = pack[i + 4 + e4];
        uint2 r0 = *(const uint2*)(hh + (size_t)p0 * 64 + 4 * l4);
        uint2 r1 = *(const uint2*)(hh + (size_t)p1 * 64 + 4 * l4);
        float2 f00 = __half22float2(*(const __half2*)&r0.x);
        float2 f01 = __half22float2(*(const __half2*)&r0.y);
        float2 f10 = __half22float2(*(const __half2*)&r1.x);
        float2 f11 = __half22float2(*(const __half2*)&r1.y);
        A.x += f00.x; A.y += f00.y; A.z += f01.x; A.w += f01.y;
        B.x += f10.x; B.y += f10.y; B.z += f11.x; B.w += f11.y;
    }
    for (; i + 3 < s1; i += 4) {
        int p = pack[i + e4];
        uint2 r = *(const uint2*)(hh + (size_t)p * 64 + 4 * l4);
        float2 f0 = __half22float2(*(const __half2*)&r.x);
        float2 f1 = __half22float2(*(const __half2*)&r.y);
        A.x += f0.x; A.y += f0.y; A.z += f1.x; A.w += f1.y;
    }
    if (i + e4 < s1) {
        int p = pack[i + e4];
        uint2 r = *(const uint2*)(hh + (size_t)p * 64 + 4 * l4);
        float2 f0 = __half22float2(*(const __half2*)&r.x);
        float2 f1 = __half22float2(*(const __half2*)&r.y);
        A.x += f0.x; A.y += f0.y; A.z += f1.x; A.w += f1.y;
    }
    A.x += B.x; A.y += B.y; A.z += B.z; A.w += B.w;
    A.x += __shfl_xor(A.x, 16); A.y += __shfl_xor(A.y, 16);
    A.z += __shfl_xor(A.z, 16); A.w += __shfl_xor(A.w, 16);
    A.x += __shfl_xor(A.x, 32); A.y += __shfl_xor(A.y, 32);
    A.z += __shfl_xor(A.z, 32); A.w += __shfl_xor(A.w, 32);

    const float di = dinv[node];
    if (lane < 16) {
        uint2 sr = *(const uint2*)(hh + (size_t)node * 64 + 4 * l4);
        float2 sf0 = __half22float2(*(const __half2*)&sr.x);
        float2 sf1 = __half22float2(*(const __half2*)&sr.y);
        h1s[wave][4 * l4 + 0] = fmaxf((A.x + sf0.x) * di + b1[4 * l4 + 0], 0.f);
        h1s[wave][4 * l4 + 1] = fmaxf((A.y + sf0.y) * di + b1[4 * l4 + 1], 0.f);
        h1s[wave][4 * l4 + 2] = fmaxf((A.z + sf1.x) * di + b1[4 * l4 + 2], 0.f);
        h1s[wave][4 * l4 + 3] = fmaxf((A.w + sf1.y) * di + b1[4 * l4 + 3], 0.f);
    }
    const int j = lane >> 4, cc = lane & 15;
    float g = 0.f;
    #pragma unroll
    for (int t = 0; t < 16; ++t) {
        int k = j * 16 + t;
        g = fmaf(h1s[wave][k], W2s[k][cc], g);
    }
    g += __shfl_xor(g, 16);
    g += __shfl_xor(g, 32);
    g *= di;                           // h2' = dinv * h2
    float go = __shfl_xor(g, 1);
    if (lane < 16 && (cc & 1) == 0) {
        *(__half2*)&h2h[(size_t)node * 16 + cc] = __floats2half2_rn(g, go);
    }
}

// ---------------- fused agg2 + self-loop + b2 + log_softmax ----------------
__global__ __launch_bounds__(256) void k_agg2_final(const int* __restrict__ starts,
                                                    const int* __restrict__ ends,
                                                    const int* __restrict__ pack,
                                                    const float* __restrict__ dinv,
                                                    const __half* __restrict__ h2h,
                                                    const float* __restrict__ b2,
                                                    float* __restrict__ out) {
    const int tid = threadIdx.x;
    const int wave = tid >> 6;
    const int lane = tid & 63;
    const int node = blockIdx.x * 4 + wave;
    const int j = lane >> 3, cp = lane & 7;   // channels 2cp, 2cp+1

    const int s0 = starts[node], s1 = ends[node];
    float2 a0 = {0.f, 0.f}, a1 = {0.f, 0.f};
    int i = s0 + j;
    for (; i + 8 < s1; i += 16) {
        int p0 = pack[i], p1 = pack[i + 8];
        float2 f0 = __half22float2(*(const __half2*)(h2h + (size_t)p0 * 16 + 2 * cp));
        float2 f1 = __half22float2(*(const __half2*)(h2h + (size_t)p1 * 16 + 2 * cp));
        a0.x += f0.x; a0.y += f0.y;
        a1.x += f1.x; a1.y += f1.y;
    }
    for (; i < s1; i += 8) {
        int p = pack[i];
        float2 f = __half22float2(*(const __half2*)(h2h + (size_t)p * 16 + 2 * cp));
        a0.x += f.x; a0.y += f.y;
    }
    float2 z;
    z.x = a0.x + a1.x;
    z.y = a0.y + a1.y;
    z.x += __shfl_xor(z.x, 8);  z.y += __shfl_xor(z.y, 8);
    z.x += __shfl_xor(z.x, 16); z.y += __shfl_xor(z.y, 16);
    z.x += __shfl_xor(z.x, 32); z.y += __shfl_xor(z.y, 32);

    const float di = dinv[node];
    float2 sf = __half22float2(*(const __half2*)(h2h + (size_t)node * 16 + 2 * cp));
    z.x = (z.x + sf.x) * di + b2[2 * cp];
    z.y = (z.y + sf.y) * di + b2[2 * cp + 1];

    float m = fmaxf(z.x, z.y);
    m = fmaxf(m, __shfl_xor(m, 1, 8));
    m = fmaxf(m, __shfl_xor(m, 2, 8));
    m = fmaxf(m, __shfl_xor(m, 4, 8));
    float ex = __expf(z.x - m), ey = __expf(z.y - m);
    float s = ex + ey;
    s += __shfl_xor(s, 1, 8);
    s += __shfl_xor(s, 2, 8);
    s += __shfl_xor(s, 4, 8);
    float ls = logf(s);
    if (j == 0) {
        float2 o;
        o.x = z.x - m - ls;
        o.y = z.y - m - ls;
        *(float2*)&out[(size_t)node * 16 + 2 * cp] = o;
    }
}

extern "C" void kernel_launch(void* const* d_in, const int* in_sizes, int n_in,
                              void* d_out, int out_size, void* d_ws, size_t ws_size,
                              hipStream_t stream) {
    const float* x  = (const float*)d_in[0];
    const int* ei   = (const int*)d_in[1];
    const float* W1 = (const float*)d_in[2];
    const float* b1 = (const float*)d_in[3];
    const float* W2 = (const float*)d_in[4];
    const float* b2 = (const float*)d_in[5];
    const int* src = ei;
    const int* dst = ei + N_EDGES;

    // workspace layout (int units): 8192+196+100000(degi)+100000+100000+100000 ints before bpack
    // = 408388 (even) -> bpack/pack 8B aligned; hh offset = (408388 + 2*NB*CAP)*4 bytes, 8B aligned
    _Float16* Bfrag = (_Float16*)d_ws;                   // 16384 halves = 8192 ints
    int*    bcur    = (int*)d_ws + 8192;                 // NB
    int*    degi    = bcur + NB;                         // N (memset with bcur region start)
    int*    starts  = degi + N_NODES;                    // N
    int*    ends    = starts + N_NODES;                  // N
    float*  dinv    = (float*)(ends + N_NODES);          // N
    int*    bpack   = (int*)(dinv + N_NODES);            // NB*CAP
    int*    pack    = bpack + NB * CAP;                  // NB*CAP
    __half* hh      = (__half*)(pack + NB * CAP);        // N*64 half
    __half* h2h     = hh + (size_t)N_NODES * 64;         // N*16 half
    float*  out     = (float*)d_out;

    hipMemsetAsync(bcur, 0, (NB + N_NODES) * sizeof(int), stream);

    k_count_deg<<<(N_EDGES + 255) / 256, 256, 0, stream>>>(dst, degi);
    k_dinv<<<(N_NODES + 255) / 256, 256, 0, stream>>>(degi, dinv);
    k_prepW1<<<64, 256, 0, stream>>>(W1, Bfrag);
    k_front<<<NFILL + NGEMM, 256, 0, stream>>>(src, dst, bcur, bpack, x, Bfrag, dinv, hh);
    k_sort_bins<<<NB, 512, 0, stream>>>(bcur, bpack, pack, starts, ends);
    k_agg1_gemm2<<<N_NODES / 4, 256, 0, stream>>>(starts, ends, pack, dinv, hh, b1, W2, h2h);
    k_agg2_final<<<N_NODES / 4, 256, 0, stream>>>(starts, ends, pack, dinv, h2h, b2, out);
}

// Round 12
// 181.365 us; speedup vs baseline: 1.3029x; 1.3029x over previous
//
#include <hip/hip_runtime.h>
#include <hip/hip_fp16.h>
#include <math.h>

#define N_NODES 100000
#define N_EDGES 1600000
#define FIN 256
#define NB 196           // ceil(100000/512): 512-node dst buckets
#define CAP 10240        // bucket capacity: mean 8163, sigma ~90 -> +22 sigma

typedef _Float16 h8 __attribute__((ext_vector_type(8)));
typedef float f4 __attribute__((ext_vector_type(4)));

// ---------------- W1 -> f16 MFMA B-fragment layout ----------------
__global__ __launch_bounds__(256) void k_prepW1(const float* __restrict__ W1, _Float16* __restrict__ Bfrag) {
    int i = blockIdx.x * 256 + threadIdx.x;   // 0..16383
    int j = i & 7, lane = (i >> 3) & 63, nt = (i >> 9) & 3, ks = i >> 11;
    int k = ks * 32 + ((lane >> 4) << 3) + j;
    int c = nt * 16 + (lane & 15);
    Bfrag[i] = (_Float16)W1[k * 64 + c];
}

// ---------------- pass A: bin edges into fixed-capacity 512-node buckets ----------------
// payload = (local_dst<<17)|src ; bucket b region = [b*CAP, b*CAP+cnt)
__global__ __launch_bounds__(256) void k_fill_bins(const int* __restrict__ src, const int* __restrict__ dst,
                                                   int* __restrict__ bcur, int* __restrict__ bpack) {
    __shared__ int hist[NB], curs[NB], bstart[NB];
    const int tid = threadIdx.x;
    for (int i = tid; i < NB; i += 256) { hist[i] = 0; curs[i] = 0; }
    __syncthreads();
    const int base = blockIdx.x * 4096;
    int eb[16], ee[16];
    #pragma unroll
    for (int k = 0; k < 16; ++k) {
        int e = base + k * 256 + tid;
        eb[k] = -1;
        if (e < N_EDGES) {
            int s = src[e], d = dst[e];
            int b = d >> 9;
            eb[k] = b;
            ee[k] = ((d & 511) << 17) | s;
            atomicAdd(&hist[b], 1);
        }
    }
    __syncthreads();
    for (int i = tid; i < NB; i += 256)
        if (hist[i] > 0) bstart[i] = i * CAP + atomicAdd(&bcur[i], hist[i]);
    __syncthreads();
    #pragma unroll
    for (int k = 0; k < 16; ++k) {
        if (eb[k] >= 0) {
            int r = atomicAdd(&curs[eb[k]], 1);
            bpack[bstart[eb[k]] + r] = ee[k];
        }
    }
}

// ---------------- pass B: per bucket -> node histogram, scan, dinv, starts/ends, sorted src ----------------
__global__ __launch_bounds__(512) void k_sort_bins(const int* __restrict__ bcur,
                                                   const int* __restrict__ bpack,
                                                   int* __restrict__ pack,
                                                   int* __restrict__ starts,
                                                   int* __restrict__ ends,
                                                   float* __restrict__ dinv) {
    __shared__ int hist[512], sd[512], cur[512];
    const int tid = threadIdx.x;
    const int b = blockIdx.x;
    const int node0 = b << 9;
    hist[tid] = 0;
    __syncthreads();
    const int s0 = b * CAP, s1 = s0 + bcur[b];
    for (int i = s0 + tid; i < s1; i += 512) atomicAdd(&hist[bpack[i] >> 17], 1);
    __syncthreads();
    const int deg = hist[tid];
    sd[tid] = deg;
    __syncthreads();
    for (int off = 1; off < 512; off <<= 1) {
        int tv = (tid >= off) ? sd[tid - off] : 0;
        __syncthreads();
        sd[tid] += tv;
        __syncthreads();
    }
    const int excl = sd[tid] - deg;
    const int n = node0 + tid;
    cur[tid] = s0 + excl;
    if (n < N_NODES) {
        starts[n] = s0 + excl;
        ends[n]   = s0 + excl + deg;
        dinv[n] = rsqrtf((float)deg + 1.0f);
    }
    __syncthreads();
    for (int i = s0 + tid; i < s1; i += 512) {
        int v = bpack[i];
        int pos = atomicAdd(&cur[v >> 17], 1);
        pack[pos] = v & 0x1FFFF;
    }
}

// ---------------- GEMM1 via MFMA: h' = dinv * (x @ W1), f16 out ----------------
__global__ __launch_bounds__(256) void k_gemm1(const float* __restrict__ x,
                                               const _Float16* __restrict__ Bfrag,
                                               const float* __restrict__ dinv,
                                               __half* __restrict__ hh) {
    const int tid = threadIdx.x;
    const int wave = tid >> 6, lane = tid & 63;
    const int lrow = lane & 15;
    const int lk = lane >> 4;
    const int row = blockIdx.x * 64 + wave * 16 + lrow;
    const int rowc = (row < N_NODES) ? row : (N_NODES - 1);
    const float di = dinv[rowc];
    const float* xp = x + (size_t)rowc * 256 + lk * 8;
    const h8* bp = (const h8*)Bfrag + lane;

    f4 acc0 = {0.f, 0.f, 0.f, 0.f};
    f4 acc1 = {0.f, 0.f, 0.f, 0.f};
    f4 acc2 = {0.f, 0.f, 0.f, 0.f};
    f4 acc3 = {0.f, 0.f, 0.f, 0.f};

    #pragma unroll 2
    for (int ks = 0; ks < 8; ++ks) {
        float4 a01 = *(const float4*)(xp + ks * 32);
        float4 a23 = *(const float4*)(xp + ks * 32 + 4);
        h8 af;
        af[0] = (_Float16)(a01.x * di); af[1] = (_Float16)(a01.y * di);
        af[2] = (_Float16)(a01.z * di); af[3] = (_Float16)(a01.w * di);
        af[4] = (_Float16)(a23.x * di); af[5] = (_Float16)(a23.y * di);
        af[6] = (_Float16)(a23.z * di); af[7] = (_Float16)(a23.w * di);
        h8 b0 = bp[(ks * 4 + 0) * 64];
        h8 b1 = bp[(ks * 4 + 1) * 64];
        h8 b2 = bp[(ks * 4 + 2) * 64];
        h8 b3 = bp[(ks * 4 + 3) * 64];
        acc0 = __builtin_amdgcn_mfma_f32_16x16x32_f16(af, b0, acc0, 0, 0, 0);
        acc1 = __builtin_amdgcn_mfma_f32_16x16x32_f16(af, b1, acc1, 0, 0, 0);
        acc2 = __builtin_amdgcn_mfma_f32_16x16x32_f16(af, b2, acc2, 0, 0, 0);
        acc3 = __builtin_amdgcn_mfma_f32_16x16x32_f16(af, b3, acc3, 0, 0, 0);
    }

    const int orow0 = blockIdx.x * 64 + wave * 16 + lk * 4;
    const bool evlane = ((lane & 1) == 0);
#define STORE_TILE(ACC, NT) { \
    _Pragma("unroll") \
    for (int r = 0; r < 4; ++r) { \
        float v = ACC[r]; \
        float o = __shfl_xor(v, 1); \
        int orow = orow0 + r; \
        if (evlane && orow < N_NODES) \
            *(__half2*)&hh[(size_t)orow * 64 + (NT) * 16 + lrow] = __floats2half2_rn(v, o); \
    } }
    STORE_TILE(acc0, 0)
    STORE_TILE(acc1, 1)
    STORE_TILE(acc2, 2)
    STORE_TILE(acc3, 3)
#undef STORE_TILE
}

// ---------------- fused agg1 + self-loop + b1 + relu + GEMM2, h2' = dinv*h2 out ----------------
// wave per node; 4 edge-slots x 16 lanes x 8B gathers, unroll 2 -> 8 edges in flight
__global__ __launch_bounds__(256) void k_agg1_gemm2(const int* __restrict__ starts,
                                                    const int* __restrict__ ends,
                                                    const int* __restrict__ pack,
                                                    const float* __restrict__ dinv,
                                                    const __half* __restrict__ hh,
                                                    const float* __restrict__ b1,
                                                    const float* __restrict__ W2,
                                                    __half* __restrict__ h2h) {
    __shared__ float W2s[64][17];
    __shared__ float h1s[4][64];
    const int tid = threadIdx.x;
    for (int i = tid; i < 64 * 16; i += 256) W2s[i >> 4][i & 15] = W2[i];
    __syncthreads();

    const int wave = tid >> 6;
    const int lane = tid & 63;
    const int node = blockIdx.x * 4 + wave;
    const int e4 = lane >> 4;        // edge slot 0..3
    const int l4 = lane & 15;        // channels 4*l4 .. 4*l4+3

    const int s0 = starts[node], s1 = ends[node];
    float4 A = {0.f, 0.f, 0.f, 0.f}, B = {0.f, 0.f, 0.f, 0.f};
    int i = s0;
    for (; i + 7 < s1; i += 8) {
        int p0 = pack[i + e4], p1 = pack[i + 4 + e4];
        uint2 r0 = *(const uint2*)(hh + (size_t)p0 * 64 + 4 * l4);
        uint2 r1 = *(const uint2*)(hh + (size_t)p1 * 64 + 4 * l4);
        float2 f00 = __half22float2(*(const __half2*)&r0.x);
        float2 f01 = __half22float2(*(const __half2*)&r0.y);
        float2 f10 = __half22float2(*(const __half2*)&r1.x);
        float2 f11 = __half22float2(*(const __half2*)&r1.y);
        A.x += f00.x; A.y += f00.y; A.z += f01.x; A.w += f01.y;
        B.x += f10.x; B.y += f10.y; B.z += f11.x; B.w += f11.y;
    }
    for (; i + 3 < s1; i += 4) {
        int p = pack[i + e4];
        uint2 r = *(const uint2*)(hh + (size_t)p * 64 + 4 * l4);
        float2 f0 = __half22float2(*(const __half2*)&r.x);
        float2 f1 = __half22float2(*(const __half2*)&r.y);
        A.x += f0.x; A.y += f0.y; A.z += f1.x; A.w += f1.y;
    }
    if (i + e4 < s1) {
        int p = pack[i + e4];
        uint2 r = *(const uint2*)(hh + (size_t)p * 64 + 4 * l4);
        float2 f0 = __half22float2(*(const __half2*)&r.x);
        float2 f1 = __half22float2(*(const __half2*)&r.y);
        A.x += f0.x; A.y += f0.y; A.z += f1.x; A.w += f1.y;
    }
    A.x += B.x; A.y += B.y; A.z += B.z; A.w += B.w;
    // reduce across the 4 edge slots (lanes 16 apart)
    A.x += __shfl_xor(A.x, 16); A.y += __shfl_xor(A.y, 16);
    A.z += __shfl_xor(A.z, 16); A.w += __shfl_xor(A.w, 16);
    A.x += __shfl_xor(A.x, 32); A.y += __shfl_xor(A.y, 32);
    A.z += __shfl_xor(A.z, 32); A.w += __shfl_xor(A.w, 32);

    const float di = dinv[node];
    if (lane < 16) {
        uint2 sr = *(const uint2*)(hh + (size_t)node * 64 + 4 * l4);
        float2 sf0 = __half22float2(*(const __half2*)&sr.x);
        float2 sf1 = __half22float2(*(const __half2*)&sr.y);
        h1s[wave][4 * l4 + 0] = fmaxf((A.x + sf0.x) * di + b1[4 * l4 + 0], 0.f);
        h1s[wave][4 * l4 + 1] = fmaxf((A.y + sf0.y) * di + b1[4 * l4 + 1], 0.f);
        h1s[wave][4 * l4 + 2] = fmaxf((A.z + sf1.x) * di + b1[4 * l4 + 2], 0.f);
        h1s[wave][4 * l4 + 3] = fmaxf((A.w + sf1.y) * di + b1[4 * l4 + 3], 0.f);
    }
    // same-wave LDS write->read (lgkmcnt-ordered)
    const int j = lane >> 4, cc = lane & 15;
    float g = 0.f;
    #pragma unroll
    for (int t = 0; t < 16; ++t) {
        int k = j * 16 + t;
        g = fmaf(h1s[wave][k], W2s[k][cc], g);
    }
    g += __shfl_xor(g, 16);
    g += __shfl_xor(g, 32);
    g *= di;                           // h2' = dinv * h2
    float go = __shfl_xor(g, 1);
    if (lane < 16 && (cc & 1) == 0) {
        *(__half2*)&h2h[(size_t)node * 16 + cc] = __floats2half2_rn(g, go);
    }
}

// ---------------- fused agg2 + self-loop + b2 + log_softmax ----------------
__global__ __launch_bounds__(256) void k_agg2_final(const int* __restrict__ starts,
                                                    const int* __restrict__ ends,
                                                    const int* __restrict__ pack,
                                                    const float* __restrict__ dinv,
                                                    const __half* __restrict__ h2h,
                                                    const float* __restrict__ b2,
                                                    float* __restrict__ out) {
    const int tid = threadIdx.x;
    const int wave = tid >> 6;
    const int lane = tid & 63;
    const int node = blockIdx.x * 4 + wave;
    const int j = lane >> 3, cp = lane & 7;   // channels 2cp, 2cp+1

    const int s0 = starts[node], s1 = ends[node];
    float2 a0 = {0.f, 0.f}, a1 = {0.f, 0.f};
    int i = s0 + j;
    for (; i + 8 < s1; i += 16) {
        int p0 = pack[i], p1 = pack[i + 8];
        float2 f0 = __half22float2(*(const __half2*)(h2h + (size_t)p0 * 16 + 2 * cp));
        float2 f1 = __half22float2(*(const __half2*)(h2h + (size_t)p1 * 16 + 2 * cp));
        a0.x += f0.x; a0.y += f0.y;
        a1.x += f1.x; a1.y += f1.y;
    }
    for (; i < s1; i += 8) {
        int p = pack[i];
        float2 f = __half22float2(*(const __half2*)(h2h + (size_t)p * 16 + 2 * cp));
        a0.x += f.x; a0.y += f.y;
    }
    float2 z;
    z.x = a0.x + a1.x;
    z.y = a0.y + a1.y;
    z.x += __shfl_xor(z.x, 8);  z.y += __shfl_xor(z.y, 8);
    z.x += __shfl_xor(z.x, 16); z.y += __shfl_xor(z.y, 16);
    z.x += __shfl_xor(z.x, 32); z.y += __shfl_xor(z.y, 32);

    const float di = dinv[node];
    float2 sf = __half22float2(*(const __half2*)(h2h + (size_t)node * 16 + 2 * cp));
    z.x = (z.x + sf.x) * di + b2[2 * cp];
    z.y = (z.y + sf.y) * di + b2[2 * cp + 1];

    float m = fmaxf(z.x, z.y);
    m = fmaxf(m, __shfl_xor(m, 1, 8));
    m = fmaxf(m, __shfl_xor(m, 2, 8));
    m = fmaxf(m, __shfl_xor(m, 4, 8));
    float ex = __expf(z.x - m), ey = __expf(z.y - m);
    float s = ex + ey;
    s += __shfl_xor(s, 1, 8);
    s += __shfl_xor(s, 2, 8);
    s += __shfl_xor(s, 4, 8);
    float ls = logf(s);
    if (j == 0) {
        float2 o;
        o.x = z.x - m - ls;
        o.y = z.y - m - ls;
        *(float2*)&out[(size_t)node * 16 + 2 * cp] = o;
    }
}

extern "C" void kernel_launch(void* const* d_in, const int* in_sizes, int n_in,
                              void* d_out, int out_size, void* d_ws, size_t ws_size,
                              hipStream_t stream) {
    const float* x  = (const float*)d_in[0];
    const int* ei   = (const int*)d_in[1];
    const float* W1 = (const float*)d_in[2];
    const float* b1 = (const float*)d_in[3];
    const float* W2 = (const float*)d_in[4];
    const float* b2 = (const float*)d_in[5];
    const int* src = ei;
    const int* dst = ei + N_EDGES;

    // workspace layout (int units): 8192+196+100000+100000+100000 = 308388 (even) -> bpack/pack 8B ok,
    // hh byte offset = (308388 + 2*NB*CAP)*4 = 17289872, divisible by 8 -> uint2 loads aligned
    _Float16* Bfrag = (_Float16*)d_ws;                   // 16384 halves = 8192 ints
    int*    bcur    = (int*)d_ws + 8192;                 // NB
    int*    starts  = bcur + NB;                         // N
    int*    ends    = starts + N_NODES;                  // N
    float*  dinv    = (float*)(ends + N_NODES);          // N
    int*    bpack   = (int*)(dinv + N_NODES);            // NB*CAP
    int*    pack    = bpack + NB * CAP;                  // NB*CAP
    __half* hh      = (__half*)(pack + NB * CAP);        // N*64 half
    __half* h2h     = hh + (size_t)N_NODES * 64;         // N*16 half
    float*  out     = (float*)d_out;

    hipMemsetAsync(bcur, 0, NB * sizeof(int), stream);

    k_prepW1<<<64, 256, 0, stream>>>(W1, Bfrag);
    k_fill_bins<<<(N_EDGES + 4095) / 4096, 256, 0, stream>>>(src, dst, bcur, bpack);
    k_sort_bins<<<NB, 512, 0, stream>>>(bcur, bpack, pack, starts, ends, dinv);
    k_gemm1<<<(N_NODES + 63) / 64, 256, 0, stream>>>(x, Bfrag, dinv, hh);
    k_agg1_gemm2<<<N_NODES / 4, 256, 0, stream>>>(starts, ends, pack, dinv, hh, b1, W2, h2h);
    k_agg2_final<<<N_NODES / 4, 256, 0, stream>>>(starts, ends, pack, dinv, h2h, b2, out);
}